// Round 6
// baseline (25.984 us; speedup 1.0000x reference)
//
#include <hip/hip_runtime.h>
#include <hip/hip_bf16.h>
#include <math.h>

#define TPB 256
#define SLAB 64  // pred points per block; grid = B * (N/SLAB)

// Single-pass chamfer: block = (batch b, 64-point pred slab).
// Targets -> registers (8 per thread, negated, + 0.5*t^2): the 256 threads
// jointly cover all 2048 targets of the batch.
// Pred slab -> LDS as (x,y,z,0.5*p^2).
// Main loop over the 64 slab points: broadcast ds_read_b128 of the point,
// each thread takes min over its 8 targets of s = 0.5 t^2 - p.t (monotone
// in d^2 = 2*(s + 0.5 p^2)), writes its candidate to L[p][tid]
// (consecutive-lane LDS writes, conflict-free).
// Merge: per 32-point chunk, 8 threads/point column-min + shfl_xor, then
// sqrt / asym / blend in-block; ONE atomicAdd(out) per block.
// No inter-kernel boundary, no global scratch, no fences.
__global__ __launch_bounds__(TPB) void chamfer_onepass_kernel(
    const float* __restrict__ pred, const float* __restrict__ targ,
    const float* __restrict__ sym_flag, float* __restrict__ out,
    int N, int B, int slabsPerBatch, float invNB) {
  __shared__ float4 sh[SLAB];       // pred (x,y,z, 0.5p^2)
  __shared__ float asy[SLAB];       // per-point asym distance
  __shared__ float L[32][TPB + 1];  // candidate mins, one 32-point chunk
  __shared__ float cv[32];          // per-leader partial blended loss

  const int b = blockIdx.x / slabsPerBatch;
  const int slab = blockIdx.x % slabsPerBatch;
  const int t = threadIdx.x;
  const int slabBase = slab * SLAB;

  // ---- this thread's 8 targets into regs (negated) + 0.5*t^2
  float ntx[8], nty[8], ntz[8], ht2[8];
  {
    const float4* tg4 = (const float4*)(targ + ((size_t)b * N + t * 8) * 3);
    float tf[24];
#pragma unroll
    for (int k = 0; k < 6; ++k) {
      const float4 v = tg4[k];
      tf[4 * k] = v.x; tf[4 * k + 1] = v.y;
      tf[4 * k + 2] = v.z; tf[4 * k + 3] = v.w;
    }
#pragma unroll
    for (int j = 0; j < 8; ++j) {
      const float x = tf[3 * j], y = tf[3 * j + 1], z = tf[3 * j + 2];
      ntx[j] = -x; nty[j] = -y; ntz[j] = -z;
      ht2[j] = 0.5f * (x * x + y * y + z * z);
    }
  }

  // ---- stage pred slab + per-point asym term
  if (t < SLAB) {
    const size_t n = (size_t)b * N + slabBase + t;
    const float px = pred[n * 3], py = pred[n * 3 + 1], pz = pred[n * 3 + 2];
    sh[t] = make_float4(px, py, pz, 0.5f * (px * px + py * py + pz * pz));
    const float dx = px - targ[n * 3];
    const float dy = py - targ[n * 3 + 1];
    const float dz = pz - targ[n * 3 + 2];
    asy[t] = sqrtf(dx * dx + dy * dy + dz * dz);
  }
  __syncthreads();

  const float f = sym_flag[b];
  const int prow = t >> 3;  // 0..31: point within chunk (reduce phase)
  const int oct = t & 7;    // 0..7 : this thread's column-octant
  float cacc = 0.f;         // leader-accumulated blended loss (2 points)

#pragma unroll
  for (int half = 0; half < 2; ++half) {
    const int pb = half * 32;
    // compute phase: candidate min over this thread's 8 targets, per point
#pragma unroll 8
    for (int p = 0; p < 32; ++p) {
      const float4 t4 = sh[pb + p];  // broadcast read
      const float s0 = fmaf(ntx[0], t4.x, fmaf(nty[0], t4.y, fmaf(ntz[0], t4.z, ht2[0])));
      const float s1 = fmaf(ntx[1], t4.x, fmaf(nty[1], t4.y, fmaf(ntz[1], t4.z, ht2[1])));
      const float s2 = fmaf(ntx[2], t4.x, fmaf(nty[2], t4.y, fmaf(ntz[2], t4.z, ht2[2])));
      const float s3 = fmaf(ntx[3], t4.x, fmaf(nty[3], t4.y, fmaf(ntz[3], t4.z, ht2[3])));
      const float s4 = fmaf(ntx[4], t4.x, fmaf(nty[4], t4.y, fmaf(ntz[4], t4.z, ht2[4])));
      const float s5 = fmaf(ntx[5], t4.x, fmaf(nty[5], t4.y, fmaf(ntz[5], t4.z, ht2[5])));
      const float s6 = fmaf(ntx[6], t4.x, fmaf(nty[6], t4.y, fmaf(ntz[6], t4.z, ht2[6])));
      const float s7 = fmaf(ntx[7], t4.x, fmaf(nty[7], t4.y, fmaf(ntz[7], t4.z, ht2[7])));
      const float m = fminf(fminf(fminf(s0, s1), fminf(s2, s3)),
                            fminf(fminf(s4, s5), fminf(s6, s7)));
      L[p][t] = m;  // lanes write consecutive addresses: conflict-free
    }
    __syncthreads();

    // reduce phase: 8 threads per point, 32 columns each, then shfl merge
    float m = 3.4e38f;
#pragma unroll 8
    for (int i = 0; i < 32; ++i) m = fminf(m, L[prow][(oct << 5) + i]);
    m = fminf(m, __shfl_xor(m, 1));
    m = fminf(m, __shfl_xor(m, 2));
    m = fminf(m, __shfl_xor(m, 4));
    if (oct == 0) {
      const int pp = pb + prow;
      const float d2 = 2.0f * (m + sh[pp].w);
      cacc += f * sqrtf(fmaxf(d2, 1e-12f)) + (1.f - f) * asy[pp];
    }
    __syncthreads();  // L reused next half / done
  }

  // ---- block total: 32 leaders -> LDS -> wave-0 butterfly -> one atomicAdd
  if (oct == 0) cv[prow] = cacc;
  __syncthreads();
  if (t < 64) {
    float v = (t < 32) ? cv[t] : 0.f;
#pragma unroll
    for (int off = 32; off > 0; off >>= 1) v += __shfl_xor(v, off);
    if (t == 0) atomicAdd(out, v * invNB);
  }
}

extern "C" void kernel_launch(void* const* d_in, const int* in_sizes, int n_in,
                              void* d_out, int out_size, void* d_ws, size_t ws_size,
                              hipStream_t stream) {
  const float* pred = (const float*)d_in[0];
  const float* targ = (const float*)d_in[1];
  const float* sym_flag = (const float*)d_in[2];
  float* out = (float*)d_out;

  const int B = in_sizes[2];            // 16
  const int N = in_sizes[0] / (B * 3);  // 2048

  const int slabsPerBatch = N / SLAB;   // 32

  hipMemsetAsync(out, 0, sizeof(float), stream);  // accumulator

  chamfer_onepass_kernel<<<B * slabsPerBatch, TPB, 0, stream>>>(
      pred, targ, sym_flag, out, N, B, slabsPerBatch,
      1.0f / (float)(N * B));
}